// Round 1
// baseline (187.821 us; speedup 1.0000x reference)
//
#include <hip/hip_runtime.h>

// Problem constants (fixed by the reference):
//   V=100000, D=128, W=5 (ctx cols = 10), N=5 (neg), B = in_sizes[0]/22
constexpr int W2   = 10;   // 2*W context columns
constexpr int NNEG = 5;    // negatives
constexpr int COLS = 22;   // 10 ctx + 1 center + 1 pos + 5 neg + 5 mask
constexpr int NBLOCKS = 2048;
constexpr int THREADS = 256;              // 4 waves/block
constexpr int WAVES_TOTAL = NBLOCKS * (THREADS / 64);

__global__ __launch_bounds__(THREADS) void sg_loss_kernel(
    const int*   __restrict__ data,
    const float* __restrict__ global_W,
    const float* __restrict__ sense_W,
    const float* __restrict__ ctx_weight,
    int B,
    float* __restrict__ partials)   // 2 floats per block
{
    const int lane = threadIdx.x & 63;
    const int wib  = threadIdx.x >> 6;                 // wave in block (0..3)
    const int wgid = blockIdx.x * (THREADS >> 6) + wib; // global wave id

    const float2* __restrict__ gW2 = reinterpret_cast<const float2*>(global_W);
    const float2* __restrict__ sW2 = reinterpret_cast<const float2*>(sense_W);
    const float2* __restrict__ cw2 = reinterpret_cast<const float2*>(ctx_weight);

    // Per-lane slice of ctx_weight: dims {2*lane, 2*lane+1} for each of 10 rows.
    float2 cw[W2];
#pragma unroll
    for (int j = 0; j < W2; ++j) cw[j] = cw2[j * 64 + lane];

    float accp = 0.f, accn = 0.f;

    for (int r = wgid; r < B; r += WAVES_TOTAL) {
        // Load the 22 index/mask ints of this row with lanes 0..21, broadcast via shfl.
        const int* __restrict__ row = data + (long long)r * COLS;
        int v = (lane < COLS) ? row[lane] : 0;

        // ctx_feats slice (2 dims per lane)
        float cfx = 0.f, cfy = 0.f;
#pragma unroll
        for (int j = 0; j < W2; ++j) {
            int idx = __shfl(v, j);
            float2 e = gW2[(long long)idx * 64 + lane];
            cfx += e.x * cw[j].x;
            cfy += e.y * cw[j].y;
        }

        // 6 dot products (1 pos + 5 neg), per-lane partials
        float dots[1 + NNEG];
        {
            int p = __shfl(v, W2 + 1);
            float2 e = sW2[(long long)p * 64 + lane];
            dots[0] = cfx * e.x + cfy * e.y;
        }
#pragma unroll
        for (int n = 0; n < NNEG; ++n) {
            int idx = __shfl(v, W2 + 2 + n);
            float2 e = sW2[(long long)idx * 64 + lane];
            dots[1 + n] = cfx * e.x + cfy * e.y;
        }

        // One 6-wide butterfly reduction across the wave
#pragma unroll
        for (int s = 1; s < 64; s <<= 1) {
#pragma unroll
            for (int k = 0; k < 1 + NNEG; ++k)
                dots[k] += __shfl_xor(dots[k], s);
        }

        // All lanes now hold the full sums; compute losses redundantly (wave-uniform).
        float pip = fminf(fmaxf(dots[0], -10.f), 10.f);
        accp += log1pf(__expf(-pip));
#pragma unroll
        for (int n = 0; n < NNEG; ++n) {
            float m   = (float)__shfl(v, W2 + 2 + NNEG + n);
            float nip = fminf(fmaxf(dots[1 + n], -10.f), 10.f);
            accn += m * log1pf(__expf(nip));
        }
    }

    // Block reduction (acc is wave-uniform; take lane 0 of each wave)
    __shared__ float sp[THREADS / 64], sn[THREADS / 64];
    if (lane == 0) { sp[wib] = accp; sn[wib] = accn; }
    __syncthreads();
    if (threadIdx.x == 0) {
        float tp = 0.f, tn = 0.f;
#pragma unroll
        for (int w = 0; w < THREADS / 64; ++w) { tp += sp[w]; tn += sn[w]; }
        partials[2 * blockIdx.x]     = tp;
        partials[2 * blockIdx.x + 1] = tn;
    }
}

// Deterministic final reduction: fixed traversal order, single block.
__global__ __launch_bounds__(256) void reduce_kernel(
    const float* __restrict__ partials, int nblocks, float* __restrict__ out)
{
    float tp = 0.f, tn = 0.f;
    for (int i = threadIdx.x; i < nblocks; i += 256) {
        tp += partials[2 * i];
        tn += partials[2 * i + 1];
    }
    __shared__ float sp[256], sn[256];
    sp[threadIdx.x] = tp; sn[threadIdx.x] = tn;
    __syncthreads();
    for (int s = 128; s > 0; s >>= 1) {
        if (threadIdx.x < s) {
            sp[threadIdx.x] += sp[threadIdx.x + s];
            sn[threadIdx.x] += sn[threadIdx.x + s];
        }
        __syncthreads();
    }
    if (threadIdx.x == 0) { out[0] = sp[0]; out[1] = sn[0]; }
}

extern "C" void kernel_launch(void* const* d_in, const int* in_sizes, int n_in,
                              void* d_out, int out_size, void* d_ws, size_t ws_size,
                              hipStream_t stream) {
    const int*   data       = (const int*)  d_in[0];
    const float* global_W   = (const float*)d_in[1];
    const float* sense_W    = (const float*)d_in[2];
    const float* ctx_weight = (const float*)d_in[3];
    // d_in[4] = window (5), d_in[5] = negative (5) — fixed constants, baked in.

    const int B = in_sizes[0] / COLS;     // 131072
    float* partials = (float*)d_ws;       // 2*NBLOCKS floats = 16 KB
    float* out      = (float*)d_out;      // {pos_loss, neg_loss}

    sg_loss_kernel<<<NBLOCKS, THREADS, 0, stream>>>(
        data, global_W, sense_W, ctx_weight, B, partials);
    reduce_kernel<<<1, 256, 0, stream>>>(partials, NBLOCKS, out);
}